// Round 2
// baseline (315.342 us; speedup 1.0000x reference)
//
#include <hip/hip_runtime.h>
#include <cstdint>
#include <math.h>

// ---------------------------------------------------------------------------
// Bit-exact replication of jax.random with threefry_partitionable=True
// (default since JAX 0.4.36):
//   split(key)        -> key[i] = threefry(key; hi=0, lo=i)   (foldlike)
//   random_bits 32b   -> o0 ^ o1 of threefry(key; hi(idx)=0, lo(idx)=idx)
//   kp, ku = split(key(42)); key data = (0,42)
//   n = clip(poisson_knuth(kp, 2.0, (B,)), 0, 127); n = where(nv>1,min(n,nv-1),0)
//   scores = where(valid, uniform(ku,(B,128)), -1); drop top-n (stable ties)
// ---------------------------------------------------------------------------

#define DH __host__ __device__ __forceinline__

DH uint32_t rotl32(uint32_t v, uint32_t r) { return (v << r) | (v >> (32u - r)); }

// Threefry-2x32, 20 rounds (matches jax threefry2x32)
DH void tf2x32(uint32_t k0, uint32_t k1, uint32_t x0, uint32_t x1,
               uint32_t& o0, uint32_t& o1) {
  const uint32_t k2 = k0 ^ k1 ^ 0x1BD11BDAu;
  x0 += k0; x1 += k1;
  x0 += x1; x1 = rotl32(x1, 13); x1 ^= x0;
  x0 += x1; x1 = rotl32(x1, 15); x1 ^= x0;
  x0 += x1; x1 = rotl32(x1, 26); x1 ^= x0;
  x0 += x1; x1 = rotl32(x1,  6); x1 ^= x0;
  x0 += k1; x1 += k2 + 1u;
  x0 += x1; x1 = rotl32(x1, 17); x1 ^= x0;
  x0 += x1; x1 = rotl32(x1, 29); x1 ^= x0;
  x0 += x1; x1 = rotl32(x1, 16); x1 ^= x0;
  x0 += x1; x1 = rotl32(x1, 24); x1 ^= x0;
  x0 += k2; x1 += k0 + 2u;
  x0 += x1; x1 = rotl32(x1, 13); x1 ^= x0;
  x0 += x1; x1 = rotl32(x1, 15); x1 ^= x0;
  x0 += x1; x1 = rotl32(x1, 26); x1 ^= x0;
  x0 += x1; x1 = rotl32(x1,  6); x1 ^= x0;
  x0 += k0; x1 += k1 + 3u;
  x0 += x1; x1 = rotl32(x1, 17); x1 ^= x0;
  x0 += x1; x1 = rotl32(x1, 29); x1 ^= x0;
  x0 += x1; x1 = rotl32(x1, 16); x1 ^= x0;
  x0 += x1; x1 = rotl32(x1, 24); x1 ^= x0;
  x0 += k1; x1 += k2 + 4u;
  x0 += x1; x1 = rotl32(x1, 13); x1 ^= x0;
  x0 += x1; x1 = rotl32(x1, 15); x1 ^= x0;
  x0 += x1; x1 = rotl32(x1, 26); x1 ^= x0;
  x0 += x1; x1 = rotl32(x1,  6); x1 ^= x0;
  x0 += k2; x1 += k0 + 5u;
  o0 = x0; o1 = x1;
}

__device__ __forceinline__ float u01(uint32_t bits) {
  // jax.random.uniform: bitcast((bits>>9)|0x3f800000) - 1.0  (exact)
  return __uint_as_float((bits >> 9) | 0x3f800000u) - 1.0f;
}

// Block = 1024 threads = 16 waves, owns 64 rows.
// Phase A: wave 0, one LANE per row, runs the Poisson(2) Knuth chain.
// Phase B: each 16-lane group owns one row; lane li owns cols li*8..li*8+7.
__global__ __launch_bounds__(1024) void rfm_kernel(
    const float* __restrict__ x, const float* __restrict__ mask,
    float* __restrict__ out, int B,
    uint32_t kp0, uint32_t kp1, uint32_t ku0, uint32_t ku1) {
  __shared__ int s_n[64];
  const int tid = (int)threadIdx.x;
  const int rowBase = (int)blockIdx.x * 64;

  if (tid < 64) {
    const int prow = rowBase + tid;
    int k = 0;
    if (prow < B) {
      uint32_t r0 = kp0, r1 = kp1;
      float lp = 0.0f;
      // JAX knuth: per iter: rng,sub = split(rng); k += (lp > -lam); lp += log(u)
      while (lp > -2.0f && k < 200) {
        ++k;
        uint32_t s0, s1, t0, t1, b0, b1;
        tf2x32(r0, r1, 0u, 1u, s0, s1);        // subkey  = tf(rng; 0,1)
        tf2x32(r0, r1, 0u, 0u, t0, t1);        // new rng = tf(rng; 0,0)
        r0 = t0; r1 = t1;
        tf2x32(s0, s1, 0u, (uint32_t)prow, b0, b1);  // bits for this row
        // correctly-rounded f32 log via f64; accumulate in f32 like XLA
        lp += (float)log((double)u01(b0 ^ b1));
      }
    }
    s_n[tid] = k - 1;
  }
  __syncthreads();

  const int row = rowBase + (tid >> 4);
  if (row >= B) return;
  const int li = tid & 15;
  const size_t base = (size_t)row * 128u + (size_t)(li * 8);
  const size_t NF = (size_t)B * 128u;  // elements per output tensor

  // ---- mask / validity
  float mv[8];
  {
    const float4 a = *(const float4*)(mask + base);
    const float4 b = *(const float4*)(mask + base + 4);
    mv[0] = a.x; mv[1] = a.y; mv[2] = a.z; mv[3] = a.w;
    mv[4] = b.x; mv[5] = b.y; mv[6] = b.z; mv[7] = b.w;
  }

  // ---- scores: uniform(ku,(B,128)); bits = o0^o1 of tf(ku; 0, flat_idx)
  float s[8];
  int nv = 0;
  const uint32_t idx0 = (uint32_t)row * 128u + (uint32_t)(li * 8);
#pragma unroll
  for (int j = 0; j < 8; ++j) {
    uint32_t b0, b1;
    tf2x32(ku0, ku1, 0u, idx0 + (uint32_t)j, b0, b1);
    const bool valid = mv[j] > 0.5f;
    s[j] = valid ? u01(b0 ^ b1) : -1.0f;
    nv += valid ? 1 : 0;
  }
  // group (16-lane) sum; lanes of a group are contiguous so xor stays in-group
#pragma unroll
  for (int off = 8; off; off >>= 1) nv += __shfl_xor(nv, off);

  int n = s_n[tid >> 4];
  n = (nv > 1) ? min(min(n, 127), nv - 1) : 0;

  // ---- drop the n highest-scoring positions (ties -> lower column, matching
  // stable argsort; top-n are always valid since n <= nv-1 and valid >= 0 > -1)
  uint32_t dropbits = 0u;
  for (int t = 0; t < n; ++t) {
    float bs = s[0];
    int bj = 0;
#pragma unroll
    for (int j = 1; j < 8; ++j) {
      if (s[j] > bs) { bs = s[j]; bj = j; }   // strict > : lowest j wins ties
    }
    int bc = (li << 3) + bj;
#pragma unroll
    for (int off = 8; off; off >>= 1) {
      const float os = __shfl_xor(bs, off);
      const int   oc = __shfl_xor(bc, off);
      if (os > bs || (os == bs && oc < bc)) { bs = os; bc = oc; }
    }
    const bool own = (bc >> 3) == li;
    const int  lj  = bc & 7;
#pragma unroll
    for (int j = 0; j < 8; ++j) {  // static indices only (avoid scratch)
      if (own && lj == j) { s[j] = -2.0f; dropbits |= (1u << j); }
    }
  }

  // ---- outputs: [x*rm ; mask*rm]
  float xv[8];
  {
    const float4 a = *(const float4*)(x + base);
    const float4 b = *(const float4*)(x + base + 4);
    xv[0] = a.x; xv[1] = a.y; xv[2] = a.z; xv[3] = a.w;
    xv[4] = b.x; xv[5] = b.y; xv[6] = b.z; xv[7] = b.w;
  }
#pragma unroll
  for (int j = 0; j < 8; ++j) {
    if ((dropbits >> j) & 1u) { xv[j] = 0.0f; mv[j] = 0.0f; }
  }
  {
    float4 o;
    o.x = xv[0]; o.y = xv[1]; o.z = xv[2]; o.w = xv[3];
    *(float4*)(out + base) = o;
    o.x = xv[4]; o.y = xv[5]; o.z = xv[6]; o.w = xv[7];
    *(float4*)(out + base + 4) = o;
    o.x = mv[0]; o.y = mv[1]; o.z = mv[2]; o.w = mv[3];
    *(float4*)(out + NF + base) = o;
    o.x = mv[4]; o.y = mv[5]; o.z = mv[6]; o.w = mv[7];
    *(float4*)(out + NF + base + 4) = o;
  }
}

extern "C" void kernel_launch(void* const* d_in, const int* in_sizes, int n_in,
                              void* d_out, int out_size, void* d_ws, size_t ws_size,
                              hipStream_t stream) {
  const float* x    = (const float*)d_in[0];
  const float* mask = (const float*)d_in[1];
  float* out = (float*)d_out;

  const int B = in_sizes[0] / 128;  // 500000

  // kp, ku = jax.random.split(jax.random.key(42)); key data = (0,42)
  // partitionable/foldlike: key[i] = full threefry output at counter (0, i)
  uint32_t kp0, kp1, ku0, ku1;
  tf2x32(0u, 42u, 0u, 0u, kp0, kp1);
  tf2x32(0u, 42u, 0u, 1u, ku0, ku1);

  const int rowsPerBlock = 64;
  const int blocks = (B + rowsPerBlock - 1) / rowsPerBlock;
  rfm_kernel<<<blocks, 1024, 0, stream>>>(x, mask, out, B, kp0, kp1, ku0, ku1);
}

// Round 3
// 237.085 us; speedup vs baseline: 1.3301x; 1.3301x over previous
//
#include <hip/hip_runtime.h>
#include <cstdint>
#include <math.h>

// ---------------------------------------------------------------------------
// Bit-exact replication of jax.random with threefry_partitionable=True:
//   split(key)      -> key[i] = threefry(key; hi=0, lo=i)  (foldlike)
//   random_bits 32b -> o0 ^ o1 of threefry(key; hi=0, lo=flat_idx)
//   kp, ku = split(key(42)); key data = (0,42)
//   n = poisson_knuth(kp, 2.0)[row]; n = where(nv>1, min(n, nv-1), 0)
//   scores = where(valid, uniform(ku,(B,128)), -1); drop top-n (stable ties)
//
// Key structural facts exploited here:
//  * The Knuth-Poisson rng split chain (rng -> subkey_it) is ROW-INDEPENDENT:
//    precomputed on the HOST (24 iterations; P(Poisson(2) >= 24) ~ 1e-17).
//  * Iteration uniforms u_it(row) = hash(subkey_it; 0, row) are then
//    independent hashes -> computed SPECULATIVELY in parallel, one per lane
//    of the row's 16-lane group. The f32 left-to-right accumulation order of
//    the reference is preserved by a serial shuffle-gather sum.
// ---------------------------------------------------------------------------

#define DH __host__ __device__ __forceinline__

DH uint32_t rotl32(uint32_t v, uint32_t r) { return (v << r) | (v >> (32u - r)); }

// Threefry-2x32, 20 rounds (matches jax threefry2x32)
DH void tf2x32(uint32_t k0, uint32_t k1, uint32_t x0, uint32_t x1,
               uint32_t& o0, uint32_t& o1) {
  const uint32_t k2 = k0 ^ k1 ^ 0x1BD11BDAu;
  x0 += k0; x1 += k1;
  x0 += x1; x1 = rotl32(x1, 13); x1 ^= x0;
  x0 += x1; x1 = rotl32(x1, 15); x1 ^= x0;
  x0 += x1; x1 = rotl32(x1, 26); x1 ^= x0;
  x0 += x1; x1 = rotl32(x1,  6); x1 ^= x0;
  x0 += k1; x1 += k2 + 1u;
  x0 += x1; x1 = rotl32(x1, 17); x1 ^= x0;
  x0 += x1; x1 = rotl32(x1, 29); x1 ^= x0;
  x0 += x1; x1 = rotl32(x1, 16); x1 ^= x0;
  x0 += x1; x1 = rotl32(x1, 24); x1 ^= x0;
  x0 += k2; x1 += k0 + 2u;
  x0 += x1; x1 = rotl32(x1, 13); x1 ^= x0;
  x0 += x1; x1 = rotl32(x1, 15); x1 ^= x0;
  x0 += x1; x1 = rotl32(x1, 26); x1 ^= x0;
  x0 += x1; x1 = rotl32(x1,  6); x1 ^= x0;
  x0 += k0; x1 += k1 + 3u;
  x0 += x1; x1 = rotl32(x1, 17); x1 ^= x0;
  x0 += x1; x1 = rotl32(x1, 29); x1 ^= x0;
  x0 += x1; x1 = rotl32(x1, 16); x1 ^= x0;
  x0 += x1; x1 = rotl32(x1, 24); x1 ^= x0;
  x0 += k1; x1 += k2 + 4u;
  x0 += x1; x1 = rotl32(x1, 13); x1 ^= x0;
  x0 += x1; x1 = rotl32(x1, 15); x1 ^= x0;
  x0 += x1; x1 = rotl32(x1, 26); x1 ^= x0;
  x0 += x1; x1 = rotl32(x1,  6); x1 ^= x0;
  x0 += k2; x1 += k0 + 5u;
  o0 = x0; o1 = x1;
}

__device__ __forceinline__ float u01(uint32_t bits) {
  // jax.random.uniform: bitcast((bits>>9)|0x3f800000) - 1.0  (exact)
  return __uint_as_float((bits >> 9) | 0x3f800000u) - 1.0f;
}

struct PoisKeys { uint32_t s0[24]; uint32_t s1[24]; };

// 256 threads/block = 16 groups of 16 lanes; one group per row.
// Lane li owns columns li*8 .. li*8+7. No LDS, no barriers.
__global__ __launch_bounds__(256) void rfm_kernel(
    const float* __restrict__ x, const float* __restrict__ mask,
    float* __restrict__ out, int B,
    uint32_t ku0, uint32_t ku1, PoisKeys pk) {
  const int tid = (int)threadIdx.x;
  const int row = (int)blockIdx.x * 16 + (tid >> 4);
  if (row >= B) return;
  const int li = tid & 15;
  const int wl = tid & 63;          // lane within wave
  const int gb = wl & 48;           // group base lane within wave
  const size_t base = (size_t)row * 128u + (size_t)(li * 8);
  const size_t NF = (size_t)B * 128u;

  // ---- issue both input loads first; latency hides under hashing
  const float4 ma = *(const float4*)(mask + base);
  const float4 mb = *(const float4*)(mask + base + 4);
  const float4 xa = *(const float4*)(x + base);
  const float4 xb = *(const float4*)(x + base + 4);

  // ---- Poisson(2): lane li speculatively computes iteration it = li
  float lg;
  {
    uint32_t b0, b1;
    tf2x32(pk.s0[li], pk.s1[li], 0u, (uint32_t)row, b0, b1);
    lg = (float)log((double)u01(b0 ^ b1));
  }
  // serial left-to-right f32 sum (reference rounding order), 8 at a time
  float lp = 0.0f;
  int k = 0;
#pragma unroll
  for (int j = 0; j < 8; ++j) {
    const float lj = __shfl(lg, gb + j);
    k += (lp > -2.0f) ? 1 : 0;
    lp += lj;
  }
  if (lp > -2.0f) {                 // P ~ 1.1e-3 per row: use lanes 8..15
#pragma unroll
    for (int j = 8; j < 16; ++j) {
      const float lj = __shfl(lg, gb + j);
      k += (lp > -2.0f) ? 1 : 0;
      lp += lj;
    }
    if (lp > -2.0f) {               // P ~ 5e-10: fresh batch, its 16..23
      uint32_t c0, c1;
      const int i2 = 16 + (li & 7);
      tf2x32(pk.s0[i2], pk.s1[i2], 0u, (uint32_t)row, c0, c1);
      const float lg2 = (float)log((double)u01(c0 ^ c1));
#pragma unroll
      for (int j = 0; j < 8; ++j) {
        const float lj = __shfl(lg2, gb + j);
        k += (lp > -2.0f) ? 1 : 0;
        lp += lj;
      }
    }
  }
  int n = k - 1;                    // 0 <= n <= 23 (clip to 127 is a no-op)

  // ---- validity + scores: uniform(ku,(B,128)); bits = o0^o1(tf(ku; 0, idx))
  float mv[8] = {ma.x, ma.y, ma.z, ma.w, mb.x, mb.y, mb.z, mb.w};
  float s[8];
  int nv = 0;
  const uint32_t idx0 = (uint32_t)row * 128u + (uint32_t)(li * 8);
#pragma unroll
  for (int j = 0; j < 8; ++j) {
    uint32_t b0, b1;
    tf2x32(ku0, ku1, 0u, idx0 + (uint32_t)j, b0, b1);
    const bool valid = mv[j] > 0.5f;
    s[j] = valid ? u01(b0 ^ b1) : -1.0f;
    nv += valid ? 1 : 0;
  }
#pragma unroll
  for (int off = 8; off; off >>= 1) nv += __shfl_xor(nv, off);  // group sum

  n = (nv > 1) ? min(n, nv - 1) : 0;

  // ---- drop the n highest-scoring positions (ties -> lower column index,
  // matching stable argsort; top-n always valid since n <= nv-1)
  uint32_t dropbits = 0u;
  for (int t = 0; t < n; ++t) {
    float bs = s[0];
    int bj = 0;
#pragma unroll
    for (int j = 1; j < 8; ++j) {
      if (s[j] > bs) { bs = s[j]; bj = j; }   // strict >: lowest j wins ties
    }
    int bc = (li << 3) + bj;
#pragma unroll
    for (int off = 8; off; off >>= 1) {       // group butterfly argmax
      const float os = __shfl_xor(bs, off);
      const int   oc = __shfl_xor(bc, off);
      if (os > bs || (os == bs && oc < bc)) { bs = os; bc = oc; }
    }
    const bool own = (bc >> 3) == li;
    const int  lj  = bc & 7;
#pragma unroll
    for (int j = 0; j < 8; ++j) {             // static indices only
      if (own && lj == j) { s[j] = -2.0f; dropbits |= (1u << j); }
    }
  }

  // ---- outputs: [x*rm ; mask*rm]
  float xv[8] = {xa.x, xa.y, xa.z, xa.w, xb.x, xb.y, xb.z, xb.w};
#pragma unroll
  for (int j = 0; j < 8; ++j) {
    if ((dropbits >> j) & 1u) { xv[j] = 0.0f; mv[j] = 0.0f; }
  }
  {
    float4 o;
    o.x = xv[0]; o.y = xv[1]; o.z = xv[2]; o.w = xv[3];
    *(float4*)(out + base) = o;
    o.x = xv[4]; o.y = xv[5]; o.z = xv[6]; o.w = xv[7];
    *(float4*)(out + base + 4) = o;
    o.x = mv[0]; o.y = mv[1]; o.z = mv[2]; o.w = mv[3];
    *(float4*)(out + NF + base) = o;
    o.x = mv[4]; o.y = mv[5]; o.z = mv[6]; o.w = mv[7];
    *(float4*)(out + NF + base + 4) = o;
  }
}

extern "C" void kernel_launch(void* const* d_in, const int* in_sizes, int n_in,
                              void* d_out, int out_size, void* d_ws, size_t ws_size,
                              hipStream_t stream) {
  const float* x    = (const float*)d_in[0];
  const float* mask = (const float*)d_in[1];
  float* out = (float*)d_out;

  const int B = in_sizes[0] / 128;  // 500000

  // kp, ku = jax.random.split(jax.random.key(42)); key data = (0,42)
  // partitionable/foldlike: key[i] = full threefry output at counter (0, i)
  uint32_t kp0, kp1, ku0, ku1;
  tf2x32(0u, 42u, 0u, 0u, kp0, kp1);
  tf2x32(0u, 42u, 0u, 1u, ku0, ku1);

  // Host-precompute the Poisson rng-split chain (row-independent):
  // per iter: subkey = tf(rng; 0,1); rng = tf(rng; 0,0)
  PoisKeys pk;
  {
    uint32_t r0 = kp0, r1 = kp1;
    for (int it = 0; it < 24; ++it) {
      uint32_t s0, s1, t0, t1;
      tf2x32(r0, r1, 0u, 1u, s0, s1);
      tf2x32(r0, r1, 0u, 0u, t0, t1);
      pk.s0[it] = s0; pk.s1[it] = s1;
      r0 = t0; r1 = t1;
    }
  }

  const int rowsPerBlock = 16;      // 256 threads, 16-lane group per row
  const int blocks = (B + rowsPerBlock - 1) / rowsPerBlock;
  rfm_kernel<<<blocks, 256, 0, stream>>>(x, mask, out, B, ku0, ku1, pk);
}